// Round 5
// baseline (97.507 us; speedup 1.0000x reference)
//
#include <hip/hip_runtime.h>

// ConditionalDense: out[b,u] = sum_d x[b,d]*kernel[cls[b],d,u] + bias[cls[b],u]
// B=2048, D=512, U=512, C=100, all float32.
// R4: S_CHUNK=32 (halves W re-reads vs 16), x staged via global_load_lds,
// W ring-3 staged via global_load_lds with counted vmcnt + raw barriers.
// Full D per block -> exact one-writer stores, no atomics.

constexpr int C_CLS   = 100;
constexpr int B_N     = 2048;
constexpr int D_DIM   = 512;
constexpr int U_DIM   = 512;
constexpr int S_CHUNK = 32;     // samples per chunk
constexpr int MAX_CHUNKS = 164; // >= worst case (2048+100*31)/32 = 161
constexpr int TU      = 256;    // u-columns per block
constexpr int PROWS   = 16;     // d-rows per staged W piece (16 KB)
constexpr int PIECES  = D_DIM / PROWS;   // 32
constexpr int NQ      = 3;      // W ring depth
constexpr int NWG     = 2 * MAX_CHUNKS;  // 328 = 8*41 (XCD swizzle bijective)

// ---------------- fused sort kernel (single block, 1024 threads) ----------------

__global__ void k_sort(const int* __restrict__ cls, int* __restrict__ order,
                       int* __restrict__ total_chunks, int* __restrict__ chunk_cls,
                       int* __restrict__ chunk_start, int* __restrict__ chunk_len) {
    __shared__ int s_cnt[128], s_off[128], s_chk[128], s_cur[128], s_base[128];
    int tid = threadIdx.x;
    if (tid < 128) s_cnt[tid] = 0;
    __syncthreads();
    for (int i = tid; i < B_N; i += 1024) atomicAdd(&s_cnt[cls[i]], 1);
    __syncthreads();
    int cnt = 0, nch = 0;
    if (tid < 128) {
        cnt = (tid < C_CLS) ? s_cnt[tid] : 0;
        nch = (cnt + S_CHUNK - 1) / S_CHUNK;
        s_off[tid] = cnt; s_chk[tid] = nch;
    }
    __syncthreads();
    for (int st = 1; st < 128; st <<= 1) {   // Hillis-Steele inclusive scan
        int a = 0, b = 0;
        if (tid >= st && tid < 128) { a = s_off[tid - st]; b = s_chk[tid - st]; }
        __syncthreads();
        if (tid < 128) { s_off[tid] += a; s_chk[tid] += b; }
        __syncthreads();
    }
    if (tid < C_CLS) {
        int off = s_off[tid] - cnt;   // exclusive prefix of counts
        int cb  = s_chk[tid] - nch;   // exclusive prefix of chunk counts
        s_base[tid] = off;
        s_cur[tid]  = 0;
        for (int j = 0; j < nch; ++j) {
            chunk_cls[cb + j]   = tid;
            chunk_start[cb + j] = off + j * S_CHUNK;
            chunk_len[cb + j]   = min(S_CHUNK, cnt - j * S_CHUNK);
        }
    }
    if (tid == 127) *total_chunks = s_chk[127];
    __syncthreads();
    for (int i = tid; i < B_N; i += 1024) {
        int c = cls[i];
        int p = atomicAdd(&s_cur[c], 1);
        order[s_base[c] + p] = i;
    }
}

// ---------------- main kernel ----------------
// Block = (chunk, 256-u-tile), 256 thr / 4 waves. Wave wv owns samples
// 8wv..8wv+7; lane owns u = u0 + lane*4. W pieces (16x256 f32, 16 KB)
// DMA'd into a 3-deep LDS ring; x rows DMA'd into xs (padding rows
// clamped to sample 0, never stored).

#define ISSUE(pi, qq) do {                                                    \
    const int db_ = (pi) * PROWS;                                             \
    _Pragma("unroll")                                                         \
    for (int j_ = 0; j_ < 4; ++j_) {                                          \
        const int r_ = wv * 4 + j_;                                           \
        const float* gp_ = Wg + (size_t)(db_ + r_) * U_DIM + lane * 4;        \
        __builtin_amdgcn_global_load_lds(                                     \
            (const __attribute__((address_space(1))) void*)gp_,               \
            (__attribute__((address_space(3))) void*)&wbuf[qq][r_][0],        \
            16, 0, 0);                                                        \
    }                                                                         \
} while (0)

#define ISSUE_X() do {                                                        \
    const int s0_ = sidx[0];                                                  \
    _Pragma("unroll")                                                         \
    for (int j_ = 0; j_ < 16; ++j_) {                                         \
        const int seg_ = wv * 16 + j_;                                        \
        const int s_ = seg_ >> 1, h_ = seg_ & 1;                              \
        int b_ = sidx[s_]; if (b_ < 0) b_ = s0_;                              \
        const float* gp_ = x + (size_t)b_ * D_DIM + h_ * 256 + lane * 4;      \
        __builtin_amdgcn_global_load_lds(                                     \
            (const __attribute__((address_space(1))) void*)gp_,               \
            (__attribute__((address_space(3))) void*)&xs[s_][h_ * 256],       \
            16, 0, 0);                                                        \
    }                                                                         \
} while (0)

#define COMPUTE(pi, qq) do {                                                  \
    const int dbase_ = (pi) * PROWS;                                          \
    _Pragma("unroll")                                                         \
    for (int g4 = 0; g4 < PROWS / 4; ++g4) {                                  \
        float4 w0 = *reinterpret_cast<const float4*>(&wbuf[qq][4*g4+0][lane*4]); \
        float4 w1 = *reinterpret_cast<const float4*>(&wbuf[qq][4*g4+1][lane*4]); \
        float4 w2 = *reinterpret_cast<const float4*>(&wbuf[qq][4*g4+2][lane*4]); \
        float4 w3 = *reinterpret_cast<const float4*>(&wbuf[qq][4*g4+3][lane*4]); \
        _Pragma("unroll")                                                     \
        for (int k = 0; k < 8; ++k) {                                         \
            float4 xq = *reinterpret_cast<const float4*>(&xs[8*wv + k][dbase_ + 4*g4]); \
            acc[k].x = fmaf(xq.x, w0.x, acc[k].x);                            \
            acc[k].x = fmaf(xq.y, w1.x, acc[k].x);                            \
            acc[k].x = fmaf(xq.z, w2.x, acc[k].x);                            \
            acc[k].x = fmaf(xq.w, w3.x, acc[k].x);                            \
            acc[k].y = fmaf(xq.x, w0.y, acc[k].y);                            \
            acc[k].y = fmaf(xq.y, w1.y, acc[k].y);                            \
            acc[k].y = fmaf(xq.z, w2.y, acc[k].y);                            \
            acc[k].y = fmaf(xq.w, w3.y, acc[k].y);                            \
            acc[k].z = fmaf(xq.x, w0.z, acc[k].z);                            \
            acc[k].z = fmaf(xq.y, w1.z, acc[k].z);                            \
            acc[k].z = fmaf(xq.z, w2.z, acc[k].z);                            \
            acc[k].z = fmaf(xq.w, w3.z, acc[k].z);                            \
            acc[k].w = fmaf(xq.x, w0.w, acc[k].w);                            \
            acc[k].w = fmaf(xq.y, w1.w, acc[k].w);                            \
            acc[k].w = fmaf(xq.z, w2.w, acc[k].w);                            \
            acc[k].w = fmaf(xq.w, w3.w, acc[k].w);                            \
        }                                                                     \
    }                                                                         \
} while (0)

// One pipelined step: wait piece pi landed (NCNT outstanding allowed),
// barrier, compute, barrier, issue piece pi+3 into the freed ring slot.
#define STEP(pi, qq, NCNT) do {                                               \
    asm volatile("s_waitcnt vmcnt(" #NCNT ")" ::: "memory");                  \
    __builtin_amdgcn_s_barrier();                                             \
    COMPUTE(pi, qq);                                                          \
    asm volatile("" ::: "memory");                                            \
    __builtin_amdgcn_s_barrier();                                             \
    if ((pi) + NQ < PIECES) ISSUE((pi) + NQ, qq);                             \
} while (0)

__launch_bounds__(256, 1)
__global__ void k_main(const float* __restrict__ x, const float* __restrict__ kern,
                       const float* __restrict__ bias, const int* __restrict__ order,
                       const int* __restrict__ total_chunks,
                       const int* __restrict__ chunk_cls,
                       const int* __restrict__ chunk_start,
                       const int* __restrict__ chunk_len,
                       float* __restrict__ out) {
    // XCD-aware swizzle (bijective: NWG % 8 == 0).
    int lin   = blockIdx.x;
    int g     = (lin & 7) * (NWG / 8) + (lin >> 3);
    int chunk = g >> 1;
    int ytile = g & 1;
    if (chunk >= *total_chunks) return;   // block-uniform exit (before barriers)

    int tid  = threadIdx.x;
    int lane = tid & 63;
    int wv   = tid >> 6;

    int c     = chunk_cls[chunk];
    int start = chunk_start[chunk];
    int len   = chunk_len[chunk];
    int u0    = ytile * TU;

    __shared__ float wbuf[NQ][PROWS][TU];  // 48 KB
    __shared__ float xs[S_CHUNK][D_DIM];   // 64 KB
    __shared__ int   sidx[S_CHUNK];

    const float* Wg = kern + (size_t)c * (D_DIM * U_DIM) + u0;

    // ---- prologue ----
    if (tid < S_CHUNK) sidx[tid] = (tid < len) ? order[start + tid] : -1;
    asm volatile("s_waitcnt lgkmcnt(0)" ::: "memory");
    __builtin_amdgcn_s_barrier();          // sidx visible

    ISSUE_X();                             // 16 loads/wave: xs rows
    ISSUE(0, 0);                           // 4 loads/wave each: W pieces 0..2
    ISSUE(1, 1);
    ISSUE(2, 2);

    float4 acc[8];
    #pragma unroll
    for (int k = 0; k < 8; ++k) acc[k] = make_float4(0.f, 0.f, 0.f, 0.f);

    // ---- main loop: 32 pieces, ring-3, steady vmcnt(8) = 2 pieces in flight.
    // i=0 wait also covers xs (x's 16 are the oldest outstanding loads).
    #pragma unroll 1
    for (int i = 0; i < PIECES - 2; i += 3) {   // i = 0,3,...,27 -> pieces 0..29
        STEP(i,     0, 8);
        STEP(i + 1, 1, 8);
        STEP(i + 2, 2, 8);
    }
    STEP(PIECES - 2, 0, 4);                // piece 30
    STEP(PIECES - 1, 1, 0);                // piece 31

    // ---- epilogue: direct stores, one writer per output element ----
    float4 bb = *reinterpret_cast<const float4*>(&bias[c * U_DIM + u0 + lane * 4]);
    #pragma unroll
    for (int k = 0; k < 8; ++k) {
        int b = sidx[8 * wv + k];
        if (b >= 0) {
            float4 o = make_float4(acc[k].x + bb.x, acc[k].y + bb.y,
                                   acc[k].z + bb.z, acc[k].w + bb.w);
            *reinterpret_cast<float4*>(&out[(size_t)b * U_DIM + u0 + lane * 4]) = o;
        }
    }
}

// ---------------- launch ----------------

extern "C" void kernel_launch(void* const* d_in, const int* in_sizes, int n_in,
                              void* d_out, int out_size, void* d_ws, size_t ws_size,
                              hipStream_t stream) {
    const float* x    = (const float*)d_in[0];
    const int*   cls  = (const int*)d_in[1];
    const float* kern = (const float*)d_in[2];
    const float* bias = (const float*)d_in[3];
    float*       out  = (float*)d_out;

    int* ws           = (int*)d_ws;
    int* order        = ws;          // 2048
    int* total_chunks = ws + 2048;   // 1
    int* chunk_cls    = ws + 2112;   // 164
    int* chunk_start  = ws + 2304;   // 164
    int* chunk_len    = ws + 2496;   // 164

    hipLaunchKernelGGL(k_sort, dim3(1), dim3(1024), 0, stream,
                       cls, order, total_chunks, chunk_cls, chunk_start, chunk_len);
    hipLaunchKernelGGL(k_main, dim3(NWG), dim3(256), 0, stream,
                       x, kern, bias, order, total_chunks, chunk_cls, chunk_start, chunk_len, out);
}